// Round 10
// baseline (72.768 us; speedup 1.0000x reference)
//
#include <hip/hip_runtime.h>

#define CCH  512
#define HF   50
#define WF   50
#define NROI 256
#define XT_BYTES (HF * WF * CCH * sizeof(float))     // 5.12 MB transposed map
#define WS_NEEDED (XT_BYTES + 64)
#define ROWSTR (WF * 256)                            // floats between y rows (within cg256)
#define OBSTR 258                                    // LDS stage stride (floats)
#define TUNITS (HF * 8)                              // 400 transpose units

// ---------- Fused kernel: transpose (phase 1) + pool (phase 2), one dispatch ----------
// Grid 512 x 512 thr = exactly 2 blocks/CU, fully resident (LDS 50.6KB, VGPR<=128).
// Phase 1: blocks 0..399 transpose [C][H][W] -> [cg256][H][W][256]; device-scope
// semaphore releases everyone. Phase 2: identical to proven R8 pool body.
__global__ __launch_bounds__(512, 4) void roipool_fused(
    const float* __restrict__ x,
    const float* __restrict__ rois,
    float* __restrict__ out,
    float* __restrict__ xt,
    int* __restrict__ done)
{
    __shared__ union {
        float tile[64][51];                          // phase 1 (13 KB)
        float ob[49 * OBSTR];                        // phase 2 (50.6 KB)
    } sm;

    const int blk = blockIdx.x;
    const int t   = threadIdx.x;
    const int wv  = t >> 6, lane = t & 63;

    // ---------------- phase 1: transpose (blocks 0..399) ----------------
    if (blk < TUNITS) {
        const int y  = blk >> 3;
        const int c0 = (blk & 7) << 6;
        if (t < 256) {
            for (int r = 0; r < 16; ++r) {
                const int cl = ((t >> 6) & 3) * 16 + r;
                if (lane < WF)
                    sm.tile[cl][lane] = x[(c0 + cl) * (HF * WF) + y * WF + lane];
            }
        }
        __syncthreads();
        if (t < 256) {
            const int g   = c0 >> 8;                 // 256-group id (0/1)
            const int cin = c0 & 255;
            for (int k = 0; k < 13; ++k) {
                const int xx = ((t >> 6) & 3) + 4 * k;
                if (xx < WF)
                    xt[((size_t)g * (HF * WF) + y * WF + xx) * 256 + cin + lane]
                        = sm.tile[lane][xx];
            }
        }
        __syncthreads();
        if (t == 0) {
            __threadfence();                         // publish xt stores
            atomicAdd(done, 1);
        }
    }
    // wait for all 400 transpose units (read-only spin, s_sleep backoff)
    if (t == 0) {
        while (__hip_atomic_load(done, __ATOMIC_RELAXED, __HIP_MEMORY_SCOPE_AGENT) < TUNITS)
            __builtin_amdgcn_s_sleep(4);
        __threadfence();                             // acquire
    }
    __syncthreads();

    // ---------------- phase 2: pool (all 512 blocks; R8 body) ----------------
    const int n  = blk >> 1;
    const int cg = blk & 1;                          // matches XCD parity (blk%8 & 1)

    // scale 50/800 = 0.0625 exact; (int) trunc == jnp astype(int32)
    const float4 rv = *(const float4*)(rois + n * 4);
    const int rx = (int)(rv.x * 0.0625f);
    const int ry = (int)(rv.y * 0.0625f);
    const int sw = (int)(rv.z * 0.0625f) + 1;        // 6..23
    const int sh = (int)(rv.w * 0.0625f) + 1;        // 6..23

    const float* part = xt + (size_t)cg * (HF * WF * 256) + 4 * lane;

#define M4(a) { m.x = fmaxf(m.x,(a).x); m.y = fmaxf(m.y,(a).y); \
                m.z = fmaxf(m.z,(a).z); m.w = fmaxf(m.w,(a).w); }
#define LD(k) (*(const float4*)(rp + (k) * 256))

    for (int task = wv; task < 49; task += 8) {
        const int ph = task / 7;
        const int pw = task - ph * 7;
        const int ys = ry + (ph * sh) / 7;
        const int ye = ry + ((ph + 1) * sh + 6) / 7;     // <= 47
        const int xs = rx + (pw * sw) / 7;
        const int xe = rx + ((pw + 1) * sw + 6) / 7;     // <= 47
        const int yspan = ye - ys;                       // 1..5
        const int xspan = xe - xs;                       // 1..5
        const float* rp = part + (ys * WF + xs) * 256;

        float4 m = make_float4(-INFINITY, -INFINITY, -INFINITY, -INFINITY);
        switch (xspan) {                                 // wave-uniform scalar branch
        case 1: {
            float4 a0 = LD(0);
            for (int y = 1; y < yspan; ++y) {
                rp += ROWSTR; float4 b0 = LD(0);
                M4(a0); a0 = b0;
            }
            M4(a0);
        } break;
        case 2: {
            float4 a0 = LD(0), a1 = LD(1);
            for (int y = 1; y < yspan; ++y) {
                rp += ROWSTR; float4 b0 = LD(0), b1 = LD(1);
                M4(a0); M4(a1); a0 = b0; a1 = b1;
            }
            M4(a0); M4(a1);
        } break;
        case 3: {
            float4 a0 = LD(0), a1 = LD(1), a2 = LD(2);
            for (int y = 1; y < yspan; ++y) {
                rp += ROWSTR; float4 b0 = LD(0), b1 = LD(1), b2 = LD(2);
                M4(a0); M4(a1); M4(a2); a0 = b0; a1 = b1; a2 = b2;
            }
            M4(a0); M4(a1); M4(a2);
        } break;
        case 4: {
            float4 a0 = LD(0), a1 = LD(1), a2 = LD(2), a3 = LD(3);
            for (int y = 1; y < yspan; ++y) {
                rp += ROWSTR; float4 b0 = LD(0), b1 = LD(1), b2 = LD(2), b3 = LD(3);
                M4(a0); M4(a1); M4(a2); M4(a3);
                a0 = b0; a1 = b1; a2 = b2; a3 = b3;
            }
            M4(a0); M4(a1); M4(a2); M4(a3);
        } break;
        default: {
            float4 a0 = LD(0), a1 = LD(1), a2 = LD(2), a3 = LD(3), a4 = LD(4);
            for (int y = 1; y < yspan; ++y) {
                rp += ROWSTR; float4 b0 = LD(0), b1 = LD(1), b2 = LD(2), b3 = LD(3), b4 = LD(4);
                M4(a0); M4(a1); M4(a2); M4(a3); M4(a4);
                a0 = b0; a1 = b1; a2 = b2; a3 = b3; a4 = b4;
            }
            M4(a0); M4(a1); M4(a2); M4(a3); M4(a4);
        } break;
        }

        *(float2*)&sm.ob[task * OBSTR + 4 * lane]     = make_float2(m.x, m.y);
        *(float2*)&sm.ob[task * OBSTR + 4 * lane + 2] = make_float2(m.z, m.w);
    }
#undef LD
#undef M4
    __syncthreads();

    // coalesced contiguous NT burst: 256 ch x 49 tasks = 12544 floats
    float* op = out + (size_t)(n * CCH + cg * 256) * 49;
    {
        int c = t / 49, task = t - (t / 49) * 49;
        for (int i = t; i < 256 * 49; i += 512) {
            __builtin_nontemporal_store(sm.ob[task * OBSTR + c], &op[i]);
            task += 22; c += 10;                     // 512 = 10*49 + 22
            if (task >= 49) { task -= 49; c += 1; }
        }
    }
}

// ---------- Fallback (direct) if ws too small ----------
__global__ __launch_bounds__(256) void roipool_direct(
    const float* __restrict__ x, const float* __restrict__ rois,
    float* __restrict__ out, int total)
{
    const int stride = gridDim.x * blockDim.x;
    for (int idx = blockIdx.x * blockDim.x + threadIdx.x; idx < total; idx += stride) {
        int n = idx / (CCH * 49), rem = idx - n * (CCH * 49);
        int c = rem / 49, pp = rem - c * 49;
        int ph = pp / 7, pw = pp - ph * 7;
        const float* r = rois + n * 4;
        int rx = (int)(r[0] * 0.0625f), ry = (int)(r[1] * 0.0625f);
        int sw = (int)(r[2] * 0.0625f) + 1, sh = (int)(r[3] * 0.0625f) + 1;
        int ys = ry + (ph * sh) / 7, ye = ry + ((ph + 1) * sh + 6) / 7;
        int xs = rx + (pw * sw) / 7, xe = rx + ((pw + 1) * sw + 6) / 7;
        const float* f = x + c * (HF * WF);
        float m = -INFINITY;
        for (int y = ys; y < ye; ++y)
            for (int xx = xs; xx < xe; ++xx)
                m = fmaxf(m, f[y * WF + xx]);
        out[idx] = m;
    }
}

extern "C" void kernel_launch(void* const* d_in, const int* in_sizes, int n_in,
                              void* d_out, int out_size, void* d_ws, size_t ws_size,
                              hipStream_t stream) {
    const float* x    = (const float*)d_in[0];   // (1, 512, 50, 50)
    const float* rois = (const float*)d_in[2];   // (256, 4)
    float* out = (float*)d_out;                  // (256, 512, 7, 7) fp32

    if (ws_size >= WS_NEEDED) {
        float* xt  = (float*)d_ws;
        int* done  = (int*)((char*)d_ws + XT_BYTES);
        hipMemsetAsync(done, 0, sizeof(int), stream);      // graph-capture-legal
        roipool_fused<<<512, 512, 0, stream>>>(x, rois, out, xt, done);
    } else {
        const int total = NROI * CCH * 49;
        roipool_direct<<<2048, 256, 0, stream>>>(x, rois, out, total);
    }
}

// Round 11
// 24.992 us; speedup vs baseline: 2.9116x; 2.9116x over previous
//
#include <hip/hip_runtime.h>

#define CCH  512
#define HF   50
#define WF   50
#define NROI 256
#define WS_NEEDED (HF * WF * CCH * sizeof(float))    // ws holds bf16 xt (2.56MB) easily
#define ROWSTR (WF * 256)                            // elements between y rows (within cg256)
#define OBSTR 258                                    // LDS stage stride (floats)

// ---------- Kernel 1: transpose+convert [C][H][W] f32 -> [cg256][H][W][256] bf16 ----------
__global__ __launch_bounds__(256) void transpose_kernel(
    const float* __restrict__ x, unsigned short* __restrict__ xt)
{
    __shared__ float tile[64][51];                 // odd stride: conflict-free
    const int y  = blockIdx.x >> 3;
    const int c0 = (blockIdx.x & 7) << 6;
    const int t  = threadIdx.x;
    const int wv = t >> 6, lane = t & 63;

    for (int r = 0; r < 16; ++r) {
        const int cl = wv * 16 + r;
        if (lane < WF)
            tile[cl][lane] = x[(c0 + cl) * (HF * WF) + y * WF + lane];
    }
    __syncthreads();

    const int g   = c0 >> 8;                       // 256-group id (0/1)
    const int cin = c0 & 255;
    for (int k = 0; k < 13; ++k) {
        const int xx = (t >> 6) + 4 * k;
        if (xx < WF) {
            const unsigned int b = __float_as_uint(tile[lane][xx]);
            const unsigned short h =
                (unsigned short)((b + 0x7fffu + ((b >> 16) & 1u)) >> 16); // RNE f32->bf16
            xt[((size_t)g * (HF * WF) + y * WF + xx) * 256 + cin + lane] = h;
        }
    }
}

// ---------- Kernel 2: pool from bf16 blocked-transposed map ----------
// Block = (n, cg of 256 channels): 512 blocks x 512 threads (8 waves), 2 blocks/CU.
// Lane = 4 channels via uint2 (8B) loads; unpack bf16->f32 exact (shl/and); fmax f32.
__global__ __launch_bounds__(512, 4) void roipool_t_kernel(
    const unsigned short* __restrict__ xt,
    const float* __restrict__ rois,
    float* __restrict__ out)
{
    __shared__ float ob[49 * OBSTR];               // 50.6 KB staged outputs (f32)

    const int n  = blockIdx.x >> 1;
    const int cg = blockIdx.x & 1;
    const int t  = threadIdx.x;
    const int wv = t >> 6, lane = t & 63;

    // scale 50/800 = 0.0625 exact; (int) trunc == jnp astype(int32)
    const float4 rv = *(const float4*)(rois + n * 4);
    const int rx = (int)(rv.x * 0.0625f);
    const int ry = (int)(rv.y * 0.0625f);
    const int sw = (int)(rv.z * 0.0625f) + 1;      // 6..23
    const int sh = (int)(rv.w * 0.0625f) + 1;      // 6..23

    const unsigned short* part = xt + (size_t)cg * (HF * WF * 256) + 4 * lane;

#define M4(d) { m.x = fmaxf(m.x, __uint_as_float((d).x << 16)); \
                m.y = fmaxf(m.y, __uint_as_float((d).x & 0xffff0000u)); \
                m.z = fmaxf(m.z, __uint_as_float((d).y << 16)); \
                m.w = fmaxf(m.w, __uint_as_float((d).y & 0xffff0000u)); }
#define LD(k) (*(const uint2*)(rp + (k) * 256))

    for (int task = wv; task < 49; task += 8) {
        const int ph = task / 7;
        const int pw = task - ph * 7;
        const int ys = ry + (ph * sh) / 7;
        const int ye = ry + ((ph + 1) * sh + 6) / 7;   // <= 47
        const int xs = rx + (pw * sw) / 7;
        const int xe = rx + ((pw + 1) * sw + 6) / 7;   // <= 47
        const int yspan = ye - ys;                     // 1..5
        const int xspan = xe - xs;                     // 1..5
        const unsigned short* rp = part + (ys * WF + xs) * 256;

        float4 m = make_float4(-INFINITY, -INFINITY, -INFINITY, -INFINITY);
        switch (xspan) {                               // wave-uniform scalar branch
        case 1: {
            uint2 a0 = LD(0);
            for (int y = 1; y < yspan; ++y) {
                rp += ROWSTR; uint2 b0 = LD(0);
                M4(a0); a0 = b0;
            }
            M4(a0);
        } break;
        case 2: {
            uint2 a0 = LD(0), a1 = LD(1);
            for (int y = 1; y < yspan; ++y) {
                rp += ROWSTR; uint2 b0 = LD(0), b1 = LD(1);
                M4(a0); M4(a1); a0 = b0; a1 = b1;
            }
            M4(a0); M4(a1);
        } break;
        case 3: {
            uint2 a0 = LD(0), a1 = LD(1), a2 = LD(2);
            for (int y = 1; y < yspan; ++y) {
                rp += ROWSTR; uint2 b0 = LD(0), b1 = LD(1), b2 = LD(2);
                M4(a0); M4(a1); M4(a2); a0 = b0; a1 = b1; a2 = b2;
            }
            M4(a0); M4(a1); M4(a2);
        } break;
        case 4: {
            uint2 a0 = LD(0), a1 = LD(1), a2 = LD(2), a3 = LD(3);
            for (int y = 1; y < yspan; ++y) {
                rp += ROWSTR; uint2 b0 = LD(0), b1 = LD(1), b2 = LD(2), b3 = LD(3);
                M4(a0); M4(a1); M4(a2); M4(a3);
                a0 = b0; a1 = b1; a2 = b2; a3 = b3;
            }
            M4(a0); M4(a1); M4(a2); M4(a3);
        } break;
        default: {
            uint2 a0 = LD(0), a1 = LD(1), a2 = LD(2), a3 = LD(3), a4 = LD(4);
            for (int y = 1; y < yspan; ++y) {
                rp += ROWSTR; uint2 b0 = LD(0), b1 = LD(1), b2 = LD(2), b3 = LD(3), b4 = LD(4);
                M4(a0); M4(a1); M4(a2); M4(a3); M4(a4);
                a0 = b0; a1 = b1; a2 = b2; a3 = b3; a4 = b4;
            }
            M4(a0); M4(a1); M4(a2); M4(a3); M4(a4);
        } break;
        }

        *(float2*)&ob[task * OBSTR + 4 * lane]     = make_float2(m.x, m.y);
        *(float2*)&ob[task * OBSTR + 4 * lane + 2] = make_float2(m.z, m.w);
    }
#undef LD
#undef M4
    __syncthreads();

    // coalesced contiguous NT burst: 256 ch x 49 tasks = 12544 floats
    float* op = out + (size_t)(n * CCH + cg * 256) * 49;
    int c = t / 49, task = t - c * 49;
    for (int i = t; i < 256 * 49; i += 512) {
        __builtin_nontemporal_store(ob[task * OBSTR + c], &op[i]);
        task += 22; c += 10;                       // 512 = 10*49 + 22
        if (task >= 49) { task -= 49; c += 1; }
    }
}

// ---------- Fallback (direct) if ws too small ----------
__global__ __launch_bounds__(256) void roipool_direct(
    const float* __restrict__ x, const float* __restrict__ rois,
    float* __restrict__ out, int total)
{
    const int stride = gridDim.x * blockDim.x;
    for (int idx = blockIdx.x * blockDim.x + threadIdx.x; idx < total; idx += stride) {
        int n = idx / (CCH * 49), rem = idx - n * (CCH * 49);
        int c = rem / 49, pp = rem - c * 49;
        int ph = pp / 7, pw = pp - ph * 7;
        const float* r = rois + n * 4;
        int rx = (int)(r[0] * 0.0625f), ry = (int)(r[1] * 0.0625f);
        int sw = (int)(r[2] * 0.0625f) + 1, sh = (int)(r[3] * 0.0625f) + 1;
        int ys = ry + (ph * sh) / 7, ye = ry + ((ph + 1) * sh + 6) / 7;
        int xs = rx + (pw * sw) / 7, xe = rx + ((pw + 1) * sw + 6) / 7;
        const float* f = x + c * (HF * WF);
        float m = -INFINITY;
        for (int y = ys; y < ye; ++y)
            for (int xx = xs; xx < xe; ++xx)
                m = fmaxf(m, f[y * WF + xx]);
        out[idx] = m;
    }
}

extern "C" void kernel_launch(void* const* d_in, const int* in_sizes, int n_in,
                              void* d_out, int out_size, void* d_ws, size_t ws_size,
                              hipStream_t stream) {
    const float* x    = (const float*)d_in[0];   // (1, 512, 50, 50)
    const float* rois = (const float*)d_in[2];   // (256, 4)
    float* out = (float*)d_out;                  // (256, 512, 7, 7) fp32

    if (ws_size >= WS_NEEDED) {
        unsigned short* xt = (unsigned short*)d_ws;   // bf16 intermediate (2.56 MB)
        transpose_kernel<<<HF * 8, 256, 0, stream>>>(x, xt);
        roipool_t_kernel<<<NROI * 2, 512, 0, stream>>>(xt, rois, out);
    } else {
        const int total = NROI * CCH * 49;
        roipool_direct<<<2048, 256, 0, stream>>>(x, rois, out, total);
    }
}